// Round 12
// baseline (502.853 us; speedup 1.0000x reference)
//
#include <hip/hip_runtime.h>

#define H96 96

typedef __attribute__((ext_vector_type(8))) short bf16x8_t;
typedef __attribute__((ext_vector_type(4))) float f32x4_t;
typedef __attribute__((ext_vector_type(8))) _Float16 half8_t;

// ---------------- degrees (int) ----------------
__global__ void deg_kernel(const int* __restrict__ src, const int* __restrict__ dst,
                           int* __restrict__ dout, int* __restrict__ din, int E) {
    int e = blockIdx.x * blockDim.x + threadIdx.x;
    if (e < E) {
        atomicAdd(dout + src[e], 1);
        atomicAdd(din + dst[e], 1);
    }
}

__global__ void norm_kernel(const int* __restrict__ dO, const int* __restrict__ dI,
                            float* __restrict__ no, float* __restrict__ ni, int N) {
    int i = blockIdx.x * blockDim.x + threadIdx.x;
    if (i < N) {
        no[i] = rsqrtf(fmaxf((float)dO[i], 1.0f));
        ni[i] = rsqrtf(fmaxf((float)dI[i], 1.0f));
    }
}

// ---------------- generic exclusive scan ----------------
__global__ void scanA_kernel(const int* __restrict__ in, int* __restrict__ pre,
                             int* __restrict__ bsums, int n) {
    __shared__ int s[256];
    int i = blockIdx.x * 256 + threadIdx.x;
    int v = (i < n) ? in[i] : 0;
    s[threadIdx.x] = v;
    __syncthreads();
    for (int off = 1; off < 256; off <<= 1) {
        int t = (threadIdx.x >= off) ? s[threadIdx.x - off] : 0;
        __syncthreads();
        s[threadIdx.x] += t;
        __syncthreads();
    }
    if (i < n) pre[i] = s[threadIdx.x] - v;
    if (threadIdx.x == 255) bsums[blockIdx.x] = s[255];
}

__global__ void scanB_kernel(int* __restrict__ bsums, int nb) {
    __shared__ int s[256];
    int v = (threadIdx.x < nb) ? bsums[threadIdx.x] : 0;
    s[threadIdx.x] = v;
    __syncthreads();
    for (int off = 1; off < 256; off <<= 1) {
        int t = (threadIdx.x >= off) ? s[threadIdx.x - off] : 0;
        __syncthreads();
        s[threadIdx.x] += t;
        __syncthreads();
    }
    if (threadIdx.x < nb) bsums[threadIdx.x] = s[threadIdx.x] - v;
}

__global__ void rowfin_kernel(const int* __restrict__ pre, const int* __restrict__ bsums,
                              int* __restrict__ row_start, int* __restrict__ cursor,
                              int N, int E) {
    int i = blockIdx.x * 256 + threadIdx.x;
    if (i < N) {
        int v = pre[i] + bsums[blockIdx.x];
        row_start[i] = v;
        cursor[i] = v;
    }
    if (i == 0) row_start[N] = E;
}

// CSR scatter: packed 16B record per edge {src, perm[src], norm_out[src], 0}
__global__ void scatter_kernel(const int* __restrict__ src, const int* __restrict__ dst,
                               const int* __restrict__ perm, const float* __restrict__ norm_out,
                               int* __restrict__ cursor, int4* __restrict__ edge4, int E) {
    int e = blockIdx.x * 256 + threadIdx.x;
    if (e < E) {
        int d = dst[e];
        int s = src[e];
        int p = atomicAdd(cursor + d, 1);
        edge4[p] = make_int4(s, perm[s], __float_as_int(norm_out[s]), 0);
    }
}

// ---------------- low-contention counting sort by deg_in ----------------
__global__ void histblk_kernel(const int* __restrict__ deg, int* __restrict__ hb,
                               int N, int nb) {
    __shared__ int h[256];
    h[threadIdx.x] = 0;
    __syncthreads();
    int i = blockIdx.x * 256 + threadIdx.x;
    if (i < N) atomicAdd(&h[min(deg[i], 255)], 1);
    __syncthreads();
    hb[threadIdx.x * nb + blockIdx.x] = h[threadIdx.x];
}

__global__ void place2_kernel(const int* __restrict__ deg, const int* __restrict__ hpre,
                              const int* __restrict__ bsums, int* __restrict__ order,
                              int N, int nb) {
    __shared__ int cur[256];
    int idx = threadIdx.x * nb + blockIdx.x;
    cur[threadIdx.x] = hpre[idx] + bsums[idx >> 8];
    __syncthreads();
    int i = blockIdx.x * 256 + threadIdx.x;
    if (i < N) {
        int b = min(deg[i], 255);
        int p = atomicAdd(&cur[b], 1);
        order[p] = i;
    }
}

// ---------------- bf16 hi/lo split helper ----------------
__device__ __forceinline__ void f2bf2(float v, unsigned short& h, unsigned short& l) {
    unsigned int b = __float_as_uint(v);
    unsigned short hh = (unsigned short)((b + 0x7FFFu + ((b >> 16) & 1u)) >> 16);
    float fh = __uint_as_float(((unsigned int)hh) << 16);
    float r = v - fh;
    unsigned int rb = __float_as_uint(r);
    unsigned short ll = (unsigned short)((rb + 0x7FFFu + ((rb >> 16) & 1u)) >> 16);
    h = hh; l = ll;
}

// fused weights prep
__global__ void weights_prep(const float* __restrict__ W1, const float* __restrict__ W2,
                             const float* __restrict__ Wm, const float* __restrict__ bm,
                             unsigned short* __restrict__ w1h, unsigned short* __restrict__ w1l,
                             unsigned short* __restrict__ w2h, unsigned short* __restrict__ w2l,
                             float* __restrict__ wsum, float* __restrict__ bsum,
                             int F, int KP1) {
    int idx = blockIdx.x * 256 + threadIdx.x;
    int z1 = 96 * KP1, z2 = z1 + 96 * 96;
    if (idx < z1) {
        int n = idx / KP1, k = idx - n * KP1;
        float v = (k < F) ? W1[(size_t)k * 96 + n] : 0.f;
        unsigned short h, l;
        f2bf2(v, h, l);
        w1h[idx] = h; w1l[idx] = l;
    } else if (idx < z2) {
        int t = idx - z1;
        int n = t / 96, k = t - n * 96;
        float v = W2[(size_t)k * 96 + n];
        unsigned short h, l;
        f2bf2(v, h, l);
        w2h[t] = h; w2l[t] = l;
    } else if (idx < z2 + 96) {
        int c = idx - z2;
        float s = 0.f;
        for (int j = 0; j < 96; j++) s += Wm[c * 96 + j];
        wsum[c] = s;
    } else if (idx == z2 + 96) {
        float s = 0.f;
        for (int j = 0; j < 96; j++) s += bm[j];
        bsum[0] = s;
    }
}

// ---------------- bf16x3 MFMA GEMM, BM=64, reg-prefetch: C16 = A @ B (fp16 out) ----------------
// a_half: A is fp16 (K%32==0 assumed) else fp32 (tail-safe).
#define GBM 64
#define GBK 32
#define ASTR2 40
__global__ __launch_bounds__(256) void gemm_mfma(const void* __restrict__ Av,
                                                 const unsigned short* __restrict__ Bth,
                                                 const unsigned short* __restrict__ Btl,
                                                 _Float16* __restrict__ C16,
                                                 int M, int K, int KP, int a_half) {
    __shared__ unsigned short As_hi[GBM * ASTR2];
    __shared__ unsigned short As_lo[GBM * ASTR2];
    __shared__ unsigned short Bs_hi[96 * ASTR2];
    __shared__ unsigned short Bs_lo[96 * ASTR2];
    int tid = threadIdx.x;
    int row0 = blockIdx.x * GBM;
    int wid = tid >> 6, lane = tid & 63;
    int q = lane >> 4, mn = lane & 15;
    f32x4_t acc[6] = {};
    int nk = (K + GBK - 1) / GBK;

    const float* A32 = (const float*)Av;
    const _Float16* A16 = (const _Float16*)Av;

    float4 pa32[2];
    uint4 pa16 = make_uint4(0, 0, 0, 0);
    uint4 pbh[2], pbl[2];

#define LOAD_A(K0)                                                                   \
    if (a_half) {                                                                    \
        int r = tid >> 2, kq = tid & 3;                                              \
        int gr = row0 + r, gk = (K0) + kq * 8;                                       \
        pa16 = (gr < M) ? *(const uint4*)(A16 + (size_t)gr * K + gk)                 \
                        : make_uint4(0, 0, 0, 0);                                    \
    } else {                                                                         \
        _Pragma("unroll")                                                            \
        for (int i = 0; i < 2; i++) {                                                \
            int idx = tid + i * 256;                                                 \
            int r = idx >> 3, kq = idx & 7;                                          \
            int gr = row0 + r, gk = (K0) + kq * 4;                                   \
            float4 v = make_float4(0.f, 0.f, 0.f, 0.f);                              \
            if (gr < M) {                                                            \
                if (gk + 4 <= K) v = *(const float4*)(A32 + (size_t)gr * K + gk);    \
                else {                                                               \
                    float tv[4] = {0.f, 0.f, 0.f, 0.f};                              \
                    for (int c = 0; c < 4; c++)                                      \
                        if (gk + c < K) tv[c] = A32[(size_t)gr * K + gk + c];        \
                    v = make_float4(tv[0], tv[1], tv[2], tv[3]);                     \
                }                                                                    \
            }                                                                        \
            pa32[i] = v;                                                             \
        }                                                                            \
    }

#define LOAD_B(K0)                                                                   \
    _Pragma("unroll")                                                                \
    for (int i = 0; i < 2; i++) {                                                    \
        int idx = tid + i * 256;                                                     \
        if (idx < 384) {                                                             \
            int n = idx >> 2, kc = idx & 3;                                          \
            pbh[i] = *(const uint4*)(Bth + (size_t)n * KP + (K0) + kc * 8);          \
            pbl[i] = *(const uint4*)(Btl + (size_t)n * KP + (K0) + kc * 8);          \
        }                                                                            \
    }

    LOAD_A(0)
    LOAD_B(0)

    for (int t = 0; t < nk; t++) {
        // write staged A (convert) + B to LDS
        if (a_half) {
            int r = tid >> 2, kq = tid & 3;
            const _Float16* hp = (const _Float16*)&pa16;
            unsigned short hs[8], ls[8];
#pragma unroll
            for (int c = 0; c < 8; c++) f2bf2((float)hp[c], hs[c], ls[c]);
            uint4 hv, lv;
            hv.x = hs[0] | ((unsigned)hs[1] << 16); hv.y = hs[2] | ((unsigned)hs[3] << 16);
            hv.z = hs[4] | ((unsigned)hs[5] << 16); hv.w = hs[6] | ((unsigned)hs[7] << 16);
            lv.x = ls[0] | ((unsigned)ls[1] << 16); lv.y = ls[2] | ((unsigned)ls[3] << 16);
            lv.z = ls[4] | ((unsigned)ls[5] << 16); lv.w = ls[6] | ((unsigned)ls[7] << 16);
            *(uint4*)&As_hi[r * ASTR2 + kq * 8] = hv;
            *(uint4*)&As_lo[r * ASTR2 + kq * 8] = lv;
        } else {
#pragma unroll
            for (int i = 0; i < 2; i++) {
                int idx = tid + i * 256;
                int r = idx >> 3, kq = idx & 7;
                float4 v = pa32[i];
                unsigned short h0, l0, h1, l1, h2, l2, h3, l3;
                f2bf2(v.x, h0, l0); f2bf2(v.y, h1, l1);
                f2bf2(v.z, h2, l2); f2bf2(v.w, h3, l3);
                uint2 hv = make_uint2((unsigned)h0 | ((unsigned)h1 << 16),
                                      (unsigned)h2 | ((unsigned)h3 << 16));
                uint2 lv = make_uint2((unsigned)l0 | ((unsigned)l1 << 16),
                                      (unsigned)l2 | ((unsigned)l3 << 16));
                *(uint2*)&As_hi[r * ASTR2 + kq * 4] = hv;
                *(uint2*)&As_lo[r * ASTR2 + kq * 4] = lv;
            }
        }
#pragma unroll
        for (int i = 0; i < 2; i++) {
            int idx = tid + i * 256;
            if (idx < 384) {
                int n = idx >> 2, kc = idx & 3;
                *(uint4*)&Bs_hi[n * ASTR2 + kc * 8] = pbh[i];
                *(uint4*)&Bs_lo[n * ASTR2 + kc * 8] = pbl[i];
            }
        }
        __syncthreads();

        // prefetch next tile while computing this one
        if (t + 1 < nk) {
            int k0 = (t + 1) * GBK;
            LOAD_A(k0)
            LOAD_B(k0)
        }

        int wr = wid * 16 + mn;
        bf16x8_t ah = *(const bf16x8_t*)&As_hi[wr * ASTR2 + q * 8];
        bf16x8_t al = *(const bf16x8_t*)&As_lo[wr * ASTR2 + q * 8];
#pragma unroll
        for (int ct = 0; ct < 6; ct++) {
            int n = ct * 16 + mn;
            bf16x8_t bh = *(const bf16x8_t*)&Bs_hi[n * ASTR2 + q * 8];
            bf16x8_t bl = *(const bf16x8_t*)&Bs_lo[n * ASTR2 + q * 8];
            acc[ct] = __builtin_amdgcn_mfma_f32_16x16x32_bf16(ah, bh, acc[ct], 0, 0, 0);
            acc[ct] = __builtin_amdgcn_mfma_f32_16x16x32_bf16(ah, bl, acc[ct], 0, 0, 0);
            acc[ct] = __builtin_amdgcn_mfma_f32_16x16x32_bf16(al, bh, acc[ct], 0, 0, 0);
        }
        __syncthreads();
    }

#pragma unroll
    for (int reg = 0; reg < 4; reg++) {
        int gr = row0 + wid * 16 + q * 4 + reg;
        if (gr < M) {
#pragma unroll
            for (int ct = 0; ct < 6; ct++)
                C16[(size_t)gr * H96 + ct * 16 + mn] = (_Float16)acc[ct][reg];
        }
    }
#undef LOAD_A
#undef LOAD_B
}

// ---------------- helpers ----------------
__device__ __forceinline__ void fmah8(float4& a, float4& b, float s, half8_t v) {
    a.x = fmaf(s, (float)v[0], a.x); a.y = fmaf(s, (float)v[1], a.y);
    a.z = fmaf(s, (float)v[2], a.z); a.w = fmaf(s, (float)v[3], a.w);
    b.x = fmaf(s, (float)v[4], b.x); b.y = fmaf(s, (float)v[5], b.y);
    b.z = fmaf(s, (float)v[6], b.z); b.w = fmaf(s, (float)v[7], b.w);
}

__device__ __forceinline__ float4 prelu4(float4 acc, float ni, float4 b, float4 a) {
    float4 h;
    h.x = fmaf(acc.x, ni, b.x); h.x = (h.x >= 0.f) ? h.x : a.x * h.x;
    h.y = fmaf(acc.y, ni, b.y); h.y = (h.y >= 0.f) ? h.y : a.y * h.y;
    h.z = fmaf(acc.z, ni, b.z); h.z = (h.z >= 0.f) ? h.z : a.z * h.z;
    h.w = fmaf(acc.w, ni, b.w); h.w = (h.w >= 0.f) ? h.w : a.w * h.w;
    return h;
}

// ---------------- layer-1 dual-view SpMM over fp16 y table; writes fp16 h tables ----------------
__global__ __launch_bounds__(384) void spmm1_dual(
        const half8_t* __restrict__ yh, const int* __restrict__ row_start,
        const int4* __restrict__ edge4, const int* __restrict__ order,
        const float* __restrict__ norm_out, const float* __restrict__ norm_in,
        const float* __restrict__ b1, const float* __restrict__ a1,
        half8_t* __restrict__ h1, half8_t* __restrict__ h2, int N) {
    int g = blockIdx.x * 32 + threadIdx.y;
    if (g >= N) return;
    int d = order[g];
    int tx = threadIdx.x;
    int beg = row_start[d], end = row_start[d + 1];
    const half8_t* yt = yh + tx;
    float4 a1a = {0,0,0,0}, a1b = {0,0,0,0}, a2a = {0,0,0,0}, a2b = {0,0,0,0};
    int j = beg;
    for (; j + 8 <= end; j += 8) {
        int4 e[8];
#pragma unroll
        for (int q = 0; q < 8; q++) e[q] = edge4[j + q];
        half8_t u[8], w[8];
#pragma unroll
        for (int q = 0; q < 8; q++) u[q] = yt[(size_t)e[q].x * 12];
#pragma unroll
        for (int q = 0; q < 8; q++) w[q] = yt[(size_t)e[q].y * 12];
#pragma unroll
        for (int q = 0; q < 8; q++) {
            float n = __int_as_float(e[q].z);
            fmah8(a1a, a1b, n, u[q]);
            fmah8(a2a, a2b, n, w[q]);
        }
    }
    for (; j < end; j++) {
        int4 e = edge4[j];
        float n = __int_as_float(e.z);
        fmah8(a1a, a1b, n, yt[(size_t)e.x * 12]);
        fmah8(a2a, a2b, n, yt[(size_t)e.y * 12]);
    }
    float ni = norm_in[d], no = norm_out[d];
    float4 bb0 = ((const float4*)b1)[tx * 2], bb1 = ((const float4*)b1)[tx * 2 + 1];
    float4 aa0 = ((const float4*)a1)[tx * 2], aa1 = ((const float4*)a1)[tx * 2 + 1];
    float4 r1a = prelu4(a1a, ni, bb0, aa0), r1b = prelu4(a1b, ni, bb1, aa1);
    float4 r2a = prelu4(a2a, ni, bb0, aa0), r2b = prelu4(a2b, ni, bb1, aa1);
    half8_t o1, o2;
    o1[0] = (_Float16)(r1a.x * no); o1[1] = (_Float16)(r1a.y * no);
    o1[2] = (_Float16)(r1a.z * no); o1[3] = (_Float16)(r1a.w * no);
    o1[4] = (_Float16)(r1b.x * no); o1[5] = (_Float16)(r1b.y * no);
    o1[6] = (_Float16)(r1b.z * no); o1[7] = (_Float16)(r1b.w * no);
    o2[0] = (_Float16)(r2a.x * no); o2[1] = (_Float16)(r2a.y * no);
    o2[2] = (_Float16)(r2a.z * no); o2[3] = (_Float16)(r2a.w * no);
    o2[4] = (_Float16)(r2b.x * no); o2[5] = (_Float16)(r2b.y * no);
    o2[6] = (_Float16)(r2b.z * no); o2[7] = (_Float16)(r2b.w * no);
    h1[(size_t)d * 12 + tx] = o1;
    h2[(size_t)d * 12 + tx] = o2;
}

// ---------------- layer-2 dual-view SpMM over fp16 t table + fused final dot ----------------
__global__ __launch_bounds__(384) void spmm2_dual(
        const half8_t* __restrict__ th,
        const int* __restrict__ row_start, const int4* __restrict__ edge4,
        const int* __restrict__ order, const float* __restrict__ norm_in,
        const float* __restrict__ b2, const float* __restrict__ a2,
        const float* __restrict__ wsum, const float* __restrict__ bsum,
        float* __restrict__ outp, int N) {
    int g = blockIdx.x * 32 + threadIdx.y;
    int tx = threadIdx.x;
    int ty = threadIdx.y;
    bool valid = (g < N);
    int d = valid ? order[g] : 0;
    int beg = 0, end = 0;
    if (valid) { beg = row_start[d]; end = row_start[d + 1]; }
    const half8_t* t1 = th + tx;
    const half8_t* t2 = th + (size_t)N * 12 + tx;
    float4 a1a = {0,0,0,0}, a1b = {0,0,0,0}, a2a = {0,0,0,0}, a2b = {0,0,0,0};
    int j = beg;
    for (; j + 8 <= end; j += 8) {
        int s[8];
#pragma unroll
        for (int q = 0; q < 8; q++) s[q] = edge4[j + q].x;
        half8_t u[8], w[8];
#pragma unroll
        for (int q = 0; q < 8; q++) u[q] = t1[(size_t)s[q] * 12];
#pragma unroll
        for (int q = 0; q < 8; q++) w[q] = t2[(size_t)s[q] * 12];
#pragma unroll
        for (int q = 0; q < 8; q++) {
            fmah8(a1a, a1b, 1.f, u[q]);
            fmah8(a2a, a2b, 1.f, w[q]);
        }
    }
    for (; j < end; j++) {
        int s = edge4[j].x;
        fmah8(a1a, a1b, 1.f, t1[(size_t)s * 12]);
        fmah8(a2a, a2b, 1.f, t2[(size_t)s * 12]);
    }
    float ni = valid ? norm_in[d] : 0.f;
    float4 bb0 = ((const float4*)b2)[tx * 2], bb1 = ((const float4*)b2)[tx * 2 + 1];
    float4 aa0 = ((const float4*)a2)[tx * 2], aa1 = ((const float4*)a2)[tx * 2 + 1];
    float4 wv0 = ((const float4*)wsum)[tx * 2], wv1 = ((const float4*)wsum)[tx * 2 + 1];
    float4 r1a = prelu4(a1a, ni, bb0, aa0), r1b = prelu4(a1b, ni, bb1, aa1);
    float4 r2a = prelu4(a2a, ni, bb0, aa0), r2b = prelu4(a2b, ni, bb1, aa1);
    float p1 = r1a.x * wv0.x + r1a.y * wv0.y + r1a.z * wv0.z + r1a.w * wv0.w
             + r1b.x * wv1.x + r1b.y * wv1.y + r1b.z * wv1.z + r1b.w * wv1.w;
    float p2 = r2a.x * wv0.x + r2a.y * wv0.y + r2a.z * wv0.z + r2a.w * wv0.w
             + r2b.x * wv1.x + r2b.y * wv1.y + r2b.z * wv1.z + r2b.w * wv1.w;
    __shared__ float red1[32][12];
    __shared__ float red2[32][12];
    red1[ty][tx] = p1;
    red2[ty][tx] = p2;
    __syncthreads();
    if (tx == 0 && valid) {
        float s1 = 0.f, s2 = 0.f;
#pragma unroll
        for (int k = 0; k < 12; k++) { s1 += red1[ty][k]; s2 += red2[ty][k]; }
        outp[d] = s1 + bsum[0];
        outp[N + d] = s2 + bsum[0];
    }
}

extern "C" void kernel_launch(void* const* d_in, const int* in_sizes, int n_in,
                              void* d_out, int out_size, void* d_ws, size_t ws_size,
                              hipStream_t stream) {
    const float* x    = (const float*)d_in[0];
    const int*   src  = (const int*)d_in[1];
    const int*   dst  = (const int*)d_in[2];
    const int*   perm = (const int*)d_in[3];
    const float* W1   = (const float*)d_in[4];
    const float* b1   = (const float*)d_in[5];
    const float* a1   = (const float*)d_in[6];
    const float* W2   = (const float*)d_in[7];
    const float* b2   = (const float*)d_in[8];
    const float* a2   = (const float*)d_in[9];
    const float* Wm   = (const float*)d_in[10];
    const float* bm   = (const float*)d_in[11];
    float* out = (float*)d_out;

    int E = in_sizes[1];
    int N = in_sizes[3];
    int F = in_sizes[0] / N;               // 500
    int KP1 = ((F + GBK - 1) / GBK) * GBK; // 512

    size_t NP = ((size_t)N + 256) & ~(size_t)255;
    size_t EP = ((size_t)E + 255) & ~(size_t)255;
    int nb = (N + 255) / 256;
    size_t HB = ((size_t)256 * nb + 255) & ~(size_t)255;

    int* deg_out   = (int*)d_ws;          // NP
    int* deg_in    = deg_out + NP;        // NP
    int* pre       = deg_in + NP;         // NP
    int* row_start = pre + NP;            // NP
    int* cursor    = row_start + NP;      // NP
    int* order     = cursor + NP;         // NP
    int* bsums     = order + NP;          // 256
    int* hb        = bsums + 256;         // HB
    int* hpre      = hb + HB;             // HB
    int4* edge4    = (int4*)(hpre + HB);  // EP int4
    float* norm_out = (float*)(edge4 + EP);    // NP
    float* norm_in  = norm_out + NP;           // NP
    float* wsum     = norm_in + NP;            // 128
    float* bsum     = wsum + 128;              // 128
    unsigned short* w1th = (unsigned short*)(bsum + 128); // 96*KP1 pad 49664
    unsigned short* w1tl = w1th + 49664;
    unsigned short* w2th = w1tl + 49664;                  // 96*96 pad 9728
    unsigned short* w2tl = w2th + 9728;
    _Float16* yh  = (_Float16*)(w2tl + 9728);            // N*96 fp16
    _Float16* h1h = yh + ((size_t)N * H96 + 256);        // 2N*96 fp16 (spmm1 out)
    _Float16* th  = h1h + ((size_t)2 * N * H96 + 256);   // 2N*96 fp16 (gemm2 out)

    hipMemsetAsync(deg_out, 0, 2 * NP * sizeof(int), stream);
    deg_kernel<<<(E + 255) / 256, 256, 0, stream>>>(src, dst, deg_out, deg_in, E);
    norm_kernel<<<(N + 255) / 256, 256, 0, stream>>>(deg_out, deg_in, norm_out, norm_in, N);

    scanA_kernel<<<nb, 256, 0, stream>>>(deg_in, pre, bsums, N);
    scanB_kernel<<<1, 256, 0, stream>>>(bsums, nb);
    rowfin_kernel<<<nb, 256, 0, stream>>>(pre, bsums, row_start, cursor, N, E);
    scatter_kernel<<<(E + 255) / 256, 256, 0, stream>>>(src, dst, perm, norm_out, cursor,
                                                        edge4, E);

    histblk_kernel<<<nb, 256, 0, stream>>>(deg_in, hb, N, nb);
    int n2 = 256 * nb;
    int nb2 = (n2 + 255) / 256;
    scanA_kernel<<<nb2, 256, 0, stream>>>(hb, hpre, bsums, n2);
    scanB_kernel<<<1, 256, 0, stream>>>(bsums, nb2);
    place2_kernel<<<nb, 256, 0, stream>>>(deg_in, hpre, bsums, order, N, nb);

    int wtot = 96 * KP1 + 96 * 96 + 96 + 1;
    weights_prep<<<(wtot + 255) / 256, 256, 0, stream>>>(W1, W2, Wm, bm, w1th, w1tl,
                                                         w2th, w2tl, wsum, bsum, F, KP1);

    // yh = fp16(x @ W1) via bf16x3 MFMA
    gemm_mfma<<<(N + GBM - 1) / GBM, 256, 0, stream>>>(x, w1th, w1tl, yh, N, F, KP1, 0);

    int nsb = (N + 31) / 32;
    spmm1_dual<<<nsb, dim3(12, 32), 0, stream>>>(
        (const half8_t*)yh, row_start, edge4, order, norm_out, norm_in,
        b1, a1, (half8_t*)h1h, (half8_t*)(h1h + (size_t)N * H96), N);

    // th = fp16(h1h @ W2) via bf16x3 MFMA (A is fp16)
    gemm_mfma<<<(2 * N + GBM - 1) / GBM, 256, 0, stream>>>(h1h, w2th, w2tl, th, 2 * N, H96, H96, 1);

    spmm2_dual<<<nsb, dim3(12, 32), 0, stream>>>(
        (const half8_t*)th, row_start, edge4, order, norm_in, b2, a2,
        wsum, bsum, out, N);
}

// Round 13
// 445.234 us; speedup vs baseline: 1.1294x; 1.1294x over previous
//
#include <hip/hip_runtime.h>

#define H96 96

typedef __attribute__((ext_vector_type(8))) short bf16x8_t;
typedef __attribute__((ext_vector_type(4))) float f32x4_t;
typedef __attribute__((ext_vector_type(8))) _Float16 half8_t;

// ---------------- degrees (int) ----------------
__global__ void deg_kernel(const int* __restrict__ src, const int* __restrict__ dst,
                           int* __restrict__ dout, int* __restrict__ din, int E) {
    int e = blockIdx.x * blockDim.x + threadIdx.x;
    if (e < E) {
        atomicAdd(dout + src[e], 1);
        atomicAdd(din + dst[e], 1);
    }
}

__global__ void norm_kernel(const int* __restrict__ dO, const int* __restrict__ dI,
                            float* __restrict__ no, float* __restrict__ ni, int N) {
    int i = blockIdx.x * blockDim.x + threadIdx.x;
    if (i < N) {
        no[i] = rsqrtf(fmaxf((float)dO[i], 1.0f));
        ni[i] = rsqrtf(fmaxf((float)dI[i], 1.0f));
    }
}

// ---------------- generic exclusive scan ----------------
__global__ void scanA_kernel(const int* __restrict__ in, int* __restrict__ pre,
                             int* __restrict__ bsums, int n) {
    __shared__ int s[256];
    int i = blockIdx.x * 256 + threadIdx.x;
    int v = (i < n) ? in[i] : 0;
    s[threadIdx.x] = v;
    __syncthreads();
    for (int off = 1; off < 256; off <<= 1) {
        int t = (threadIdx.x >= off) ? s[threadIdx.x - off] : 0;
        __syncthreads();
        s[threadIdx.x] += t;
        __syncthreads();
    }
    if (i < n) pre[i] = s[threadIdx.x] - v;
    if (threadIdx.x == 255) bsums[blockIdx.x] = s[255];
}

__global__ void scanB_kernel(int* __restrict__ bsums, int nb) {
    __shared__ int s[256];
    int v = (threadIdx.x < nb) ? bsums[threadIdx.x] : 0;
    s[threadIdx.x] = v;
    __syncthreads();
    for (int off = 1; off < 256; off <<= 1) {
        int t = (threadIdx.x >= off) ? s[threadIdx.x - off] : 0;
        __syncthreads();
        s[threadIdx.x] += t;
        __syncthreads();
    }
    if (threadIdx.x < nb) bsums[threadIdx.x] = s[threadIdx.x] - v;
}

__global__ void rowfin_kernel(const int* __restrict__ pre, const int* __restrict__ bsums,
                              int* __restrict__ row_start, int* __restrict__ cursor,
                              int N, int E) {
    int i = blockIdx.x * 256 + threadIdx.x;
    if (i < N) {
        int v = pre[i] + bsums[blockIdx.x];
        row_start[i] = v;
        cursor[i] = v;
    }
    if (i == 0) row_start[N] = E;
}

// CSR scatter: packed 16B record per edge {src, perm[src], norm_out[src], 0}
__global__ void scatter_kernel(const int* __restrict__ src, const int* __restrict__ dst,
                               const int* __restrict__ perm, const float* __restrict__ norm_out,
                               int* __restrict__ cursor, int4* __restrict__ edge4, int E) {
    int e = blockIdx.x * 256 + threadIdx.x;
    if (e < E) {
        int d = dst[e];
        int s = src[e];
        int p = atomicAdd(cursor + d, 1);
        edge4[p] = make_int4(s, perm[s], __float_as_int(norm_out[s]), 0);
    }
}

// ---------------- low-contention counting sort by deg_in ----------------
__global__ void histblk_kernel(const int* __restrict__ deg, int* __restrict__ hb,
                               int N, int nb) {
    __shared__ int h[256];
    h[threadIdx.x] = 0;
    __syncthreads();
    int i = blockIdx.x * 256 + threadIdx.x;
    if (i < N) atomicAdd(&h[min(deg[i], 255)], 1);
    __syncthreads();
    hb[threadIdx.x * nb + blockIdx.x] = h[threadIdx.x];
}

__global__ void place2_kernel(const int* __restrict__ deg, const int* __restrict__ hpre,
                              const int* __restrict__ bsums, int* __restrict__ order,
                              int N, int nb) {
    __shared__ int cur[256];
    int idx = threadIdx.x * nb + blockIdx.x;
    cur[threadIdx.x] = hpre[idx] + bsums[idx >> 8];
    __syncthreads();
    int i = blockIdx.x * 256 + threadIdx.x;
    if (i < N) {
        int b = min(deg[i], 255);
        int p = atomicAdd(&cur[b], 1);
        order[p] = i;
    }
}

// ---------------- bf16 hi/lo split helper ----------------
__device__ __forceinline__ void f2bf2(float v, unsigned short& h, unsigned short& l) {
    unsigned int b = __float_as_uint(v);
    unsigned short hh = (unsigned short)((b + 0x7FFFu + ((b >> 16) & 1u)) >> 16);
    float fh = __uint_as_float(((unsigned int)hh) << 16);
    float r = v - fh;
    unsigned int rb = __float_as_uint(r);
    unsigned short ll = (unsigned short)((rb + 0x7FFFu + ((rb >> 16) & 1u)) >> 16);
    h = hh; l = ll;
}

// fused weights prep
__global__ void weights_prep(const float* __restrict__ W1, const float* __restrict__ W2,
                             const float* __restrict__ Wm, const float* __restrict__ bm,
                             unsigned short* __restrict__ w1h, unsigned short* __restrict__ w1l,
                             unsigned short* __restrict__ w2h, unsigned short* __restrict__ w2l,
                             float* __restrict__ wsum, float* __restrict__ bsum,
                             int F, int KP1) {
    int idx = blockIdx.x * 256 + threadIdx.x;
    int z1 = 96 * KP1, z2 = z1 + 96 * 96;
    if (idx < z1) {
        int n = idx / KP1, k = idx - n * KP1;
        float v = (k < F) ? W1[(size_t)k * 96 + n] : 0.f;
        unsigned short h, l;
        f2bf2(v, h, l);
        w1h[idx] = h; w1l[idx] = l;
    } else if (idx < z2) {
        int t = idx - z1;
        int n = t / 96, k = t - n * 96;
        float v = W2[(size_t)k * 96 + n];
        unsigned short h, l;
        f2bf2(v, h, l);
        w2h[t] = h; w2l[t] = l;
    } else if (idx < z2 + 96) {
        int c = idx - z2;
        float s = 0.f;
        for (int j = 0; j < 96; j++) s += Wm[c * 96 + j];
        wsum[c] = s;
    } else if (idx == z2 + 96) {
        float s = 0.f;
        for (int j = 0; j < 96; j++) s += bm[j];
        bsum[0] = s;
    }
}

// ---------------- bf16x3 MFMA GEMM, BM=64, r11-style staging (no reg prefetch) ----------------
// a_half: A is fp16 (requires K%32==0); else fp32 (tail-safe). C out is fp16.
#define GBM 64
#define GBK 32
#define ASTR2 40
__global__ __launch_bounds__(256) void gemm_mfma(const void* __restrict__ Av,
                                                 const unsigned short* __restrict__ Bth,
                                                 const unsigned short* __restrict__ Btl,
                                                 _Float16* __restrict__ C16,
                                                 int M, int K, int KP, int a_half) {
    __shared__ unsigned short As_hi[GBM * ASTR2];   // 5.1 KB
    __shared__ unsigned short As_lo[GBM * ASTR2];   // 5.1 KB
    __shared__ unsigned short Bs_hi[96 * ASTR2];    // 7.7 KB
    __shared__ unsigned short Bs_lo[96 * ASTR2];    // 7.7 KB
    int tid = threadIdx.x;
    int row0 = blockIdx.x * GBM;
    int wid = tid >> 6, lane = tid & 63;
    int q = lane >> 4, mn = lane & 15;
    f32x4_t acc[6] = {};
    int nk = (K + GBK - 1) / GBK;

    const float* A32 = (const float*)Av;
    const _Float16* A16 = (const _Float16*)Av;

    for (int t = 0; t < nk; t++) {
        int k0 = t * GBK;
        // stage A -> hi/lo bf16 in LDS
        if (a_half) {
            // 64 rows x 32 halfs = 256 x 16B chunks, 1/thread
            int r = tid >> 2, kq = tid & 3;
            int gr = row0 + r, gk = k0 + kq * 8;
            uint4 raw = (gr < M) ? *(const uint4*)(A16 + (size_t)gr * K + gk)
                                 : make_uint4(0, 0, 0, 0);
            const _Float16* hp = (const _Float16*)&raw;
            unsigned short hs[8], ls[8];
#pragma unroll
            for (int c = 0; c < 8; c++) f2bf2((float)hp[c], hs[c], ls[c]);
            uint4 hv, lv;
            hv.x = hs[0] | ((unsigned)hs[1] << 16); hv.y = hs[2] | ((unsigned)hs[3] << 16);
            hv.z = hs[4] | ((unsigned)hs[5] << 16); hv.w = hs[6] | ((unsigned)hs[7] << 16);
            lv.x = ls[0] | ((unsigned)ls[1] << 16); lv.y = ls[2] | ((unsigned)ls[3] << 16);
            lv.z = ls[4] | ((unsigned)ls[5] << 16); lv.w = ls[6] | ((unsigned)ls[7] << 16);
            *(uint4*)&As_hi[r * ASTR2 + kq * 8] = hv;
            *(uint4*)&As_lo[r * ASTR2 + kq * 8] = lv;
        } else {
            // 64 rows x 32 floats = 512 float4, 2/thread
#pragma unroll
            for (int i = 0; i < 2; i++) {
                int idx = tid + i * 256;
                int r = idx >> 3, kq = idx & 7;
                int gr = row0 + r, gk = k0 + kq * 4;
                float4 v = make_float4(0.f, 0.f, 0.f, 0.f);
                if (gr < M) {
                    if (gk + 4 <= K) {
                        v = *(const float4*)(A32 + (size_t)gr * K + gk);
                    } else {
                        float tv[4] = {0.f, 0.f, 0.f, 0.f};
                        for (int c = 0; c < 4; c++)
                            if (gk + c < K) tv[c] = A32[(size_t)gr * K + gk + c];
                        v = make_float4(tv[0], tv[1], tv[2], tv[3]);
                    }
                }
                unsigned short h0, l0, h1, l1, h2, l2, h3, l3;
                f2bf2(v.x, h0, l0); f2bf2(v.y, h1, l1);
                f2bf2(v.z, h2, l2); f2bf2(v.w, h3, l3);
                uint2 hv = make_uint2((unsigned)h0 | ((unsigned)h1 << 16),
                                      (unsigned)h2 | ((unsigned)h3 << 16));
                uint2 lv = make_uint2((unsigned)l0 | ((unsigned)l1 << 16),
                                      (unsigned)l2 | ((unsigned)l3 << 16));
                *(uint2*)&As_hi[r * ASTR2 + kq * 4] = hv;
                *(uint2*)&As_lo[r * ASTR2 + kq * 4] = lv;
            }
        }
        // stage B: 96 rows x 32 bf16 = 384 x 16B chunks (hi and lo)
#pragma unroll
        for (int i = 0; i < 2; i++) {
            int idx = tid + i * 256;
            if (idx < 384) {
                int n = idx >> 2, kc = idx & 3;
                uint4 hv = *(const uint4*)(Bth + (size_t)n * KP + k0 + kc * 8);
                uint4 lv = *(const uint4*)(Btl + (size_t)n * KP + k0 + kc * 8);
                *(uint4*)&Bs_hi[n * ASTR2 + kc * 8] = hv;
                *(uint4*)&Bs_lo[n * ASTR2 + kc * 8] = lv;
            }
        }
        __syncthreads();

        int wr = wid * 16 + mn;
        bf16x8_t ah = *(const bf16x8_t*)&As_hi[wr * ASTR2 + q * 8];
        bf16x8_t al = *(const bf16x8_t*)&As_lo[wr * ASTR2 + q * 8];
#pragma unroll
        for (int ct = 0; ct < 6; ct++) {
            int n = ct * 16 + mn;
            bf16x8_t bh = *(const bf16x8_t*)&Bs_hi[n * ASTR2 + q * 8];
            bf16x8_t bl = *(const bf16x8_t*)&Bs_lo[n * ASTR2 + q * 8];
            acc[ct] = __builtin_amdgcn_mfma_f32_16x16x32_bf16(ah, bh, acc[ct], 0, 0, 0);
            acc[ct] = __builtin_amdgcn_mfma_f32_16x16x32_bf16(ah, bl, acc[ct], 0, 0, 0);
            acc[ct] = __builtin_amdgcn_mfma_f32_16x16x32_bf16(al, bh, acc[ct], 0, 0, 0);
        }
        __syncthreads();
    }

#pragma unroll
    for (int reg = 0; reg < 4; reg++) {
        int gr = row0 + wid * 16 + q * 4 + reg;
        if (gr < M) {
#pragma unroll
            for (int ct = 0; ct < 6; ct++)
                C16[(size_t)gr * H96 + ct * 16 + mn] = (_Float16)acc[ct][reg];
        }
    }
}

// ---------------- helpers ----------------
__device__ __forceinline__ void fmah8(float4& a, float4& b, float s, half8_t v) {
    a.x = fmaf(s, (float)v[0], a.x); a.y = fmaf(s, (float)v[1], a.y);
    a.z = fmaf(s, (float)v[2], a.z); a.w = fmaf(s, (float)v[3], a.w);
    b.x = fmaf(s, (float)v[4], b.x); b.y = fmaf(s, (float)v[5], b.y);
    b.z = fmaf(s, (float)v[6], b.z); b.w = fmaf(s, (float)v[7], b.w);
}

__device__ __forceinline__ float4 prelu4(float4 acc, float ni, float4 b, float4 a) {
    float4 h;
    h.x = fmaf(acc.x, ni, b.x); h.x = (h.x >= 0.f) ? h.x : a.x * h.x;
    h.y = fmaf(acc.y, ni, b.y); h.y = (h.y >= 0.f) ? h.y : a.y * h.y;
    h.z = fmaf(acc.z, ni, b.z); h.z = (h.z >= 0.f) ? h.z : a.z * h.z;
    h.w = fmaf(acc.w, ni, b.w); h.w = (h.w >= 0.f) ? h.w : a.w * h.w;
    return h;
}

// ---------------- layer-1 dual-view SpMM over fp16 y table; writes fp16 h tables ----------------
__global__ __launch_bounds__(384) void spmm1_dual(
        const half8_t* __restrict__ yh, const int* __restrict__ row_start,
        const int4* __restrict__ edge4, const int* __restrict__ order,
        const float* __restrict__ norm_out, const float* __restrict__ norm_in,
        const float* __restrict__ b1, const float* __restrict__ a1,
        half8_t* __restrict__ h1, half8_t* __restrict__ h2, int N) {
    int g = blockIdx.x * 32 + threadIdx.y;
    if (g >= N) return;
    int d = order[g];
    int tx = threadIdx.x;
    int beg = row_start[d], end = row_start[d + 1];
    const half8_t* yt = yh + tx;
    float4 a1a = {0,0,0,0}, a1b = {0,0,0,0}, a2a = {0,0,0,0}, a2b = {0,0,0,0};
    int j = beg;
    for (; j + 8 <= end; j += 8) {
        int4 e[8];
#pragma unroll
        for (int q = 0; q < 8; q++) e[q] = edge4[j + q];
        half8_t u[8], w[8];
#pragma unroll
        for (int q = 0; q < 8; q++) u[q] = yt[(size_t)e[q].x * 12];
#pragma unroll
        for (int q = 0; q < 8; q++) w[q] = yt[(size_t)e[q].y * 12];
#pragma unroll
        for (int q = 0; q < 8; q++) {
            float n = __int_as_float(e[q].z);
            fmah8(a1a, a1b, n, u[q]);
            fmah8(a2a, a2b, n, w[q]);
        }
    }
    for (; j < end; j++) {
        int4 e = edge4[j];
        float n = __int_as_float(e.z);
        fmah8(a1a, a1b, n, yt[(size_t)e.x * 12]);
        fmah8(a2a, a2b, n, yt[(size_t)e.y * 12]);
    }
    float ni = norm_in[d], no = norm_out[d];
    float4 bb0 = ((const float4*)b1)[tx * 2], bb1 = ((const float4*)b1)[tx * 2 + 1];
    float4 aa0 = ((const float4*)a1)[tx * 2], aa1 = ((const float4*)a1)[tx * 2 + 1];
    float4 r1a = prelu4(a1a, ni, bb0, aa0), r1b = prelu4(a1b, ni, bb1, aa1);
    float4 r2a = prelu4(a2a, ni, bb0, aa0), r2b = prelu4(a2b, ni, bb1, aa1);
    half8_t o1, o2;
    o1[0] = (_Float16)(r1a.x * no); o1[1] = (_Float16)(r1a.y * no);
    o1[2] = (_Float16)(r1a.z * no); o1[3] = (_Float16)(r1a.w * no);
    o1[4] = (_Float16)(r1b.x * no); o1[5] = (_Float16)(r1b.y * no);
    o1[6] = (_Float16)(r1b.z * no); o1[7] = (_Float16)(r1b.w * no);
    o2[0] = (_Float16)(r2a.x * no); o2[1] = (_Float16)(r2a.y * no);
    o2[2] = (_Float16)(r2a.z * no); o2[3] = (_Float16)(r2a.w * no);
    o2[4] = (_Float16)(r2b.x * no); o2[5] = (_Float16)(r2b.y * no);
    o2[6] = (_Float16)(r2b.z * no); o2[7] = (_Float16)(r2b.w * no);
    h1[(size_t)d * 12 + tx] = o1;
    h2[(size_t)d * 12 + tx] = o2;
}

// ---------------- layer-2 dual-view SpMM over fp16 t table + fused final dot ----------------
__global__ __launch_bounds__(384) void spmm2_dual(
        const half8_t* __restrict__ th,
        const int* __restrict__ row_start, const int4* __restrict__ edge4,
        const int* __restrict__ order, const float* __restrict__ norm_in,
        const float* __restrict__ b2, const float* __restrict__ a2,
        const float* __restrict__ wsum, const float* __restrict__ bsum,
        float* __restrict__ outp, int N) {
    int g = blockIdx.x * 32 + threadIdx.y;
    int tx = threadIdx.x;
    int ty = threadIdx.y;
    bool valid = (g < N);
    int d = valid ? order[g] : 0;
    int beg = 0, end = 0;
    if (valid) { beg = row_start[d]; end = row_start[d + 1]; }
    const half8_t* t1 = th + tx;
    const half8_t* t2 = th + (size_t)N * 12 + tx;
    float4 a1a = {0,0,0,0}, a1b = {0,0,0,0}, a2a = {0,0,0,0}, a2b = {0,0,0,0};
    int j = beg;
    for (; j + 8 <= end; j += 8) {
        int s[8];
#pragma unroll
        for (int q = 0; q < 8; q++) s[q] = edge4[j + q].x;
        half8_t u[8], w[8];
#pragma unroll
        for (int q = 0; q < 8; q++) u[q] = t1[(size_t)s[q] * 12];
#pragma unroll
        for (int q = 0; q < 8; q++) w[q] = t2[(size_t)s[q] * 12];
#pragma unroll
        for (int q = 0; q < 8; q++) {
            fmah8(a1a, a1b, 1.f, u[q]);
            fmah8(a2a, a2b, 1.f, w[q]);
        }
    }
    for (; j < end; j++) {
        int s = edge4[j].x;
        fmah8(a1a, a1b, 1.f, t1[(size_t)s * 12]);
        fmah8(a2a, a2b, 1.f, t2[(size_t)s * 12]);
    }
    float ni = valid ? norm_in[d] : 0.f;
    float4 bb0 = ((const float4*)b2)[tx * 2], bb1 = ((const float4*)b2)[tx * 2 + 1];
    float4 aa0 = ((const float4*)a2)[tx * 2], aa1 = ((const float4*)a2)[tx * 2 + 1];
    float4 wv0 = ((const float4*)wsum)[tx * 2], wv1 = ((const float4*)wsum)[tx * 2 + 1];
    float4 r1a = prelu4(a1a, ni, bb0, aa0), r1b = prelu4(a1b, ni, bb1, aa1);
    float4 r2a = prelu4(a2a, ni, bb0, aa0), r2b = prelu4(a2b, ni, bb1, aa1);
    float p1 = r1a.x * wv0.x + r1a.y * wv0.y + r1a.z * wv0.z + r1a.w * wv0.w
             + r1b.x * wv1.x + r1b.y * wv1.y + r1b.z * wv1.z + r1b.w * wv1.w;
    float p2 = r2a.x * wv0.x + r2a.y * wv0.y + r2a.z * wv0.z + r2a.w * wv0.w
             + r2b.x * wv1.x + r2b.y * wv1.y + r2b.z * wv1.z + r2b.w * wv1.w;
    __shared__ float red1[32][12];
    __shared__ float red2[32][12];
    red1[ty][tx] = p1;
    red2[ty][tx] = p2;
    __syncthreads();
    if (tx == 0 && valid) {
        float s1 = 0.f, s2 = 0.f;
#pragma unroll
        for (int k = 0; k < 12; k++) { s1 += red1[ty][k]; s2 += red2[ty][k]; }
        outp[d] = s1 + bsum[0];
        outp[N + d] = s2 + bsum[0];
    }
}

extern "C" void kernel_launch(void* const* d_in, const int* in_sizes, int n_in,
                              void* d_out, int out_size, void* d_ws, size_t ws_size,
                              hipStream_t stream) {
    const float* x    = (const float*)d_in[0];
    const int*   src  = (const int*)d_in[1];
    const int*   dst  = (const int*)d_in[2];
    const int*   perm = (const int*)d_in[3];
    const float* W1   = (const float*)d_in[4];
    const float* b1   = (const float*)d_in[5];
    const float* a1   = (const float*)d_in[6];
    const float* W2   = (const float*)d_in[7];
    const float* b2   = (const float*)d_in[8];
    const float* a2   = (const float*)d_in[9];
    const float* Wm   = (const float*)d_in[10];
    const float* bm   = (const float*)d_in[11];
    float* out = (float*)d_out;

    int E = in_sizes[1];
    int N = in_sizes[3];
    int F = in_sizes[0] / N;               // 500
    int KP1 = ((F + GBK - 1) / GBK) * GBK; // 512

    size_t NP = ((size_t)N + 256) & ~(size_t)255;
    size_t EP = ((size_t)E + 255) & ~(size_t)255;
    int nb = (N + 255) / 256;
    size_t HB = ((size_t)256 * nb + 255) & ~(size_t)255;

    int* deg_out   = (int*)d_ws;          // NP
    int* deg_in    = deg_out + NP;        // NP
    int* pre       = deg_in + NP;         // NP
    int* row_start = pre + NP;            // NP
    int* cursor    = row_start + NP;      // NP
    int* order     = cursor + NP;         // NP
    int* bsums     = order + NP;          // 256
    int* hb        = bsums + 256;         // HB
    int* hpre      = hb + HB;             // HB
    int4* edge4    = (int4*)(hpre + HB);  // EP int4
    float* norm_out = (float*)(edge4 + EP);    // NP
    float* norm_in  = norm_out + NP;           // NP
    float* wsum     = norm_in + NP;            // 128
    float* bsum     = wsum + 128;              // 128
    unsigned short* w1th = (unsigned short*)(bsum + 128); // 96*KP1 pad 49664
    unsigned short* w1tl = w1th + 49664;
    unsigned short* w2th = w1tl + 49664;                  // 96*96 pad 9728
    unsigned short* w2tl = w2th + 9728;
    _Float16* yh  = (_Float16*)(w2tl + 9728);            // N*96 fp16
    _Float16* h1h = yh + ((size_t)N * H96 + 256);        // 2N*96 fp16 (spmm1 out)
    _Float16* th  = h1h + ((size_t)2 * N * H96 + 256);   // 2N*96 fp16 (gemm2 out)

    hipMemsetAsync(deg_out, 0, 2 * NP * sizeof(int), stream);
    deg_kernel<<<(E + 255) / 256, 256, 0, stream>>>(src, dst, deg_out, deg_in, E);
    norm_kernel<<<(N + 255) / 256, 256, 0, stream>>>(deg_out, deg_in, norm_out, norm_in, N);

    scanA_kernel<<<nb, 256, 0, stream>>>(deg_in, pre, bsums, N);
    scanB_kernel<<<1, 256, 0, stream>>>(bsums, nb);
    rowfin_kernel<<<nb, 256, 0, stream>>>(pre, bsums, row_start, cursor, N, E);
    scatter_kernel<<<(E + 255) / 256, 256, 0, stream>>>(src, dst, perm, norm_out, cursor,
                                                        edge4, E);

    histblk_kernel<<<nb, 256, 0, stream>>>(deg_in, hb, N, nb);
    int n2 = 256 * nb;
    int nb2 = (n2 + 255) / 256;
    scanA_kernel<<<nb2, 256, 0, stream>>>(hb, hpre, bsums, n2);
    scanB_kernel<<<1, 256, 0, stream>>>(bsums, nb2);
    place2_kernel<<<nb, 256, 0, stream>>>(deg_in, hpre, bsums, order, N, nb);

    int wtot = 96 * KP1 + 96 * 96 + 96 + 1;
    weights_prep<<<(wtot + 255) / 256, 256, 0, stream>>>(W1, W2, Wm, bm, w1th, w1tl,
                                                         w2th, w2tl, wsum, bsum, F, KP1);

    // yh = fp16(x @ W1) via bf16x3 MFMA
    gemm_mfma<<<(N + GBM - 1) / GBM, 256, 0, stream>>>(x, w1th, w1tl, yh, N, F, KP1, 0);

    int nsb = (N + 31) / 32;
    spmm1_dual<<<nsb, dim3(12, 32), 0, stream>>>(
        (const half8_t*)yh, row_start, edge4, order, norm_out, norm_in,
        b1, a1, (half8_t*)h1h, (half8_t*)(h1h + (size_t)N * H96), N);

    // th = fp16(h1h @ W2) via bf16x3 MFMA (A is fp16)
    gemm_mfma<<<(2 * N + GBM - 1) / GBM, 256, 0, stream>>>(h1h, w2th, w2tl, th, 2 * N, H96, H96, 1);

    spmm2_dual<<<nsb, dim3(12, 32), 0, stream>>>(
        (const half8_t*)th, row_start, edge4, order, norm_in, b2, a2,
        wsum, bsum, out, N);
}